// Round 1
// baseline (54.220 us; speedup 1.0000x reference)
//
#include <hip/hip_runtime.h>
#include <stdint.h>
#include <stddef.h>

// Problem constants
#define D_FEAT 1280
#define N_PAD  256
#define N_OUT  248
#define BM     64
#define BK     64
#define K_ITERS (D_FEAT / BK)          // 20
#define W_TILE_BYTES (N_PAD * BK * 2)  // 32 KB per K-tile of packed weights

typedef float f32x4 __attribute__((ext_vector_type(4)));
typedef short s16x8 __attribute__((ext_vector_type(8)));

__device__ __forceinline__ unsigned short f2bf(float f) {
  union { float f; unsigned int u; } v; v.f = f;
  unsigned int r = (v.u + 0x7fffu + ((v.u >> 16) & 1u)) >> 16;
  return (unsigned short)r;
}

// ---------------------------------------------------------------------------
// Pack W_final (D,8), Wp1 (8,D,6), Wp2 (8,6,D,4) into one bf16 matrix laid out
// exactly as the main kernel's LDS B-tiles expect:
//   tile kt (BK=64 k's): [n=0..255][s_phys=0..7] 16B chunks, where the chunk at
//   (n, s_phys) holds W[n][kt*64 + 8*(s_phys ^ (n&7)) .. +7]  (XOR swizzle baked
//   in, so global_load_lds is a LINEAR copy and ds_read_b128 is ~conflict-free).
// Column map: n<8 -> W_final[:,n]; 8..55 -> Wp1[i,:,c]; 56..247 -> Wp2[i,j,:,c];
// 248..255 zero padding.
// ---------------------------------------------------------------------------
__global__ __launch_bounds__(256) void pack_w_kernel(
    const float* __restrict__ Wf, const float* __restrict__ Wp1,
    const float* __restrict__ Wp2, unsigned short* __restrict__ out) {
  int idx = blockIdx.x * 256 + threadIdx.x;    // 0 .. 20*256*64-1 = 327679
  int e = idx & 7;
  int chunk = idx >> 3;
  int s_phys = chunk & 7;
  int n = (chunk >> 3) & 255;
  int kt = chunk >> 11;
  int s_log = s_phys ^ (n & 7);
  int d = kt * BK + s_log * 8 + e;
  float v = 0.0f;
  if (n < 8) {
    v = Wf[d * 8 + n];
  } else if (n < 56) {
    int m = n - 8;
    v = Wp1[((m / 6) * D_FEAT + d) * 6 + (m % 6)];
  } else if (n < 248) {
    int m = n - 56;
    v = Wp2[(((m / 24) * 6 + ((m % 24) >> 2)) * D_FEAT + d) * 4 + (m & 3)];
  }
  out[idx] = f2bf(v);
}

// ---------------------------------------------------------------------------
// Fused GEMM (bf16 MFMA) + hierarchical softmax epilogue.
// Block: 256 threads = 4 waves; BM=64 rows; each wave computes 16 rows x 256 cols.
// ---------------------------------------------------------------------------
__global__ __launch_bounds__(256) void tree_head_kernel(
    const float* __restrict__ x, const unsigned short* __restrict__ Wb,
    const float* __restrict__ b_final, const float* __restrict__ wu1,
    const float* __restrict__ b1, const float* __restrict__ wu2,
    const float* __restrict__ b2, float* __restrict__ out) {
  __shared__ char smem[65536];
  char* As = smem;            // [64 rows][64 k] bf16, XOR-swizzled (8 KB)
  char* Bs = smem + 8192;     // [256 n ][64 k] bf16, XOR-swizzled (32 KB)

  const int tid  = threadIdx.x;
  const int lane = tid & 63;
  const int wave = tid >> 6;
  const int row0 = blockIdx.x * BM;

  f32x4 acc[16];
#pragma unroll
  for (int i = 0; i < 16; ++i)
#pragma unroll
    for (int j = 0; j < 4; ++j) acc[i][j] = 0.0f;

  const int am0 = tid >> 3;   // A staging: chunk row (r=0); r=1 adds +32
  const int as0 = tid & 7;    // A staging: logical 16B slot within the row

  for (int kt = 0; kt < K_ITERS; ++kt) {
    // ---- stage B: 32 KB linear copy (pre-swizzled in global) --------------
    const char* wsrc = (const char*)Wb + (size_t)kt * W_TILE_BYTES;
#pragma unroll
    for (int i = 0; i < 8; ++i) {
      int off = i * 4096 + wave * 1024;
      __builtin_amdgcn_global_load_lds(
          (const __attribute__((address_space(1))) void*)(wsrc + off + lane * 16),
          (__attribute__((address_space(3))) void*)(Bs + off), 16, 0, 0);
    }
    // ---- stage A: fp32 -> bf16 convert, swizzled ds_write_b128 ------------
#pragma unroll
    for (int rr = 0; rr < 2; ++rr) {
      int m = am0 + rr * 32;
      const float* src = x + (size_t)(row0 + m) * D_FEAT + kt * BK + as0 * 8;
      f32x4 f0 = *(const f32x4*)src;
      f32x4 f1 = *(const f32x4*)(src + 4);
      s16x8 pk;
#pragma unroll
      for (int j = 0; j < 4; ++j) pk[j] = (short)f2bf(f0[j]);
#pragma unroll
      for (int j = 0; j < 4; ++j) pk[4 + j] = (short)f2bf(f1[j]);
      *(s16x8*)(As + m * 128 + ((as0 ^ (m & 7)) << 4)) = pk;
    }
    __syncthreads();

    // ---- compute: 2 k-steps x 16 col-frags of 16x16x32 bf16 MFMA ----------
    const int mrow = wave * 16 + (lane & 15);
#pragma unroll
    for (int ks = 0; ks < 2; ++ks) {
      int sl = ks * 4 + (lane >> 4);    // logical 16B slot (8 bf16 of k)
      s16x8 a = *(const s16x8*)(As + mrow * 128 + ((sl ^ (mrow & 7)) << 4));
#pragma unroll
      for (int nf = 0; nf < 16; ++nf) {
        int n = nf * 16 + (lane & 15);
        s16x8 b = *(const s16x8*)(Bs + n * 128 + ((sl ^ (n & 7)) << 4));
        acc[nf] = __builtin_amdgcn_mfma_f32_16x16x32_bf16(a, b, acc[nf], 0, 0, 0);
      }
    }
    __syncthreads();
  }

  // ---- epilogue: logits -> LDS, column-major stride 65 (bank-conflict-free
  //      for both the fragment writes and the per-row reads) -----------------
  float* Ls = (float*)smem;   // Ls[col*65 + row], col < 248
  const int c0 = lane & 15;
  const int r4 = wave * 16 + ((lane >> 4) << 2);
#pragma unroll
  for (int nf = 0; nf < 16; ++nf) {
    int col = nf * 16 + c0;
    if (col < N_OUT) {
#pragma unroll
      for (int i = 0; i < 4; ++i) Ls[col * 65 + r4 + i] = acc[nf][i];
    }
  }
  __syncthreads();

  // 4 threads per row: part p owns roots i = 2p,2p+1 and level-2 groups 12p..12p+11
  const int r = tid & 63;
  const int part = tid >> 6;
  float* orow = out + (size_t)(row0 + r) * N_OUT;

  if (part == 0) {
#pragma unroll
    for (int i = 0; i < 8; ++i) orow[i] = Ls[i * 65 + r] + b_final[i];
  }

  float u2loc[2][6];
#pragma unroll
  for (int ii = 0; ii < 2; ++ii) {
    int i = part * 2 + ii;
    float ui = Ls[i * 65 + r] + b_final[i];
    float lg[6];
    float mx = -1e30f;
#pragma unroll
    for (int c = 0; c < 6; ++c) {
      lg[c] = Ls[(8 + i * 6 + c) * 65 + r] + ui * wu1[i * 6 + c] + b1[i * 6 + c];
      mx = fmaxf(mx, lg[c]);
    }
    float s = 0.0f;
#pragma unroll
    for (int c = 0; c < 6; ++c) { lg[c] = __expf(lg[c] - mx); s += lg[c]; }
    float sc = ui / s;      // p1 * u1
#pragma unroll
    for (int c = 0; c < 6; ++c) {
      float v = lg[c] * sc;
      u2loc[ii][c] = v;
      orow[8 + i * 6 + c] = v;
    }
  }

#pragma unroll
  for (int gg = 0; gg < 12; ++gg) {
    int g = part * 12 + gg;          // level-2 group (i,j): i=g/6, j=g%6
    float ug = u2loc[gg / 6][gg % 6];
    float lg[4];
    float mx = -1e30f;
#pragma unroll
    for (int c = 0; c < 4; ++c) {
      lg[c] = Ls[(56 + g * 4 + c) * 65 + r] + ug * wu2[g * 4 + c] + b2[g * 4 + c];
      mx = fmaxf(mx, lg[c]);
    }
    float s = 0.0f;
#pragma unroll
    for (int c = 0; c < 4; ++c) { lg[c] = __expf(lg[c] - mx); s += lg[c]; }
    float sc = ug / s;               // p2 * u2
    f32x4 o;
#pragma unroll
    for (int c = 0; c < 4; ++c) o[c] = lg[c] * sc;
    *(f32x4*)(orow + 56 + g * 4) = o;   // 16B-aligned (248*4 and 224 are /16)
  }
}

// ---------------------------------------------------------------------------
extern "C" void kernel_launch(void* const* d_in, const int* in_sizes, int n_in,
                              void* d_out, int out_size, void* d_ws, size_t ws_size,
                              hipStream_t stream) {
  const float* x   = (const float*)d_in[0];
  const float* Wf  = (const float*)d_in[1];
  const float* bf  = (const float*)d_in[2];
  const float* Wp1 = (const float*)d_in[3];
  const float* wu1 = (const float*)d_in[4];
  const float* b1  = (const float*)d_in[5];
  const float* Wp2 = (const float*)d_in[6];
  const float* wu2 = (const float*)d_in[7];
  const float* b2  = (const float*)d_in[8];
  float* out = (float*)d_out;
  unsigned short* Wb = (unsigned short*)d_ws;   // 655,360 B packed bf16 weights

  pack_w_kernel<<<1280, 256, 0, stream>>>(Wf, Wp1, Wp2, Wb);
  tree_head_kernel<<<16384 / BM, 256, 0, stream>>>(x, Wb, bf, wu1, b1, wu2, b2, out);
}

// Round 2
// 47.315 us; speedup vs baseline: 1.1459x; 1.1459x over previous
//
#include <hip/hip_runtime.h>
#include <stdint.h>
#include <stddef.h>

// Problem constants
#define D_FEAT 1280
#define N_PAD  256
#define N_OUT  248
#define BM     32
#define BK     64
#define K_ITERS (D_FEAT / BK)          // 20
#define W_TILE_BYTES (N_PAD * BK * 2)  // 32 KB per K-tile of packed weights

typedef float f32x4 __attribute__((ext_vector_type(4)));
typedef short s16x8 __attribute__((ext_vector_type(8)));

__device__ __forceinline__ unsigned short f2bf(float f) {
  union { float f; unsigned int u; } v; v.f = f;
  unsigned int r = (v.u + 0x7fffu + ((v.u >> 16) & 1u)) >> 16;
  return (unsigned short)r;
}

// ---------------------------------------------------------------------------
// Pack W_final (D,8), Wp1 (8,D,6), Wp2 (8,6,D,4) into one bf16 matrix laid out
// exactly as the main kernel's LDS B-tiles expect:
//   tile kt (BK=64 k's): [n=0..255][s_phys=0..7] 16B chunks, where the chunk at
//   (n, s_phys) holds W[n][kt*64 + 8*(s_phys ^ (n&7)) .. +7]  (XOR swizzle baked
//   in, so global_load_lds is a LINEAR copy and ds_read_b128 is ~conflict-free).
// Column map: n<8 -> W_final[:,n]; 8..55 -> Wp1[i,:,c]; 56..247 -> Wp2[i,j,:,c];
// 248..255 zero padding.
// ---------------------------------------------------------------------------
__global__ __launch_bounds__(256) void pack_w_kernel(
    const float* __restrict__ Wf, const float* __restrict__ Wp1,
    const float* __restrict__ Wp2, unsigned short* __restrict__ out) {
  int idx = blockIdx.x * 256 + threadIdx.x;    // 0 .. 20*256*64-1 = 327679
  int e = idx & 7;
  int chunk = idx >> 3;
  int s_phys = chunk & 7;
  int n = (chunk >> 3) & 255;
  int kt = chunk >> 11;
  int s_log = s_phys ^ (n & 7);
  int d = kt * BK + s_log * 8 + e;
  float v = 0.0f;
  if (n < 8) {
    v = Wf[d * 8 + n];
  } else if (n < 56) {
    int m = n - 8;
    v = Wp1[((m / 6) * D_FEAT + d) * 6 + (m % 6)];
  } else if (n < 248) {
    int m = n - 56;
    v = Wp2[(((m / 24) * 6 + ((m % 24) >> 2)) * D_FEAT + d) * 4 + (m & 3)];
  }
  out[idx] = f2bf(v);
}

// ---------------------------------------------------------------------------
// Fused GEMM (bf16 MFMA) + hierarchical softmax epilogue.
// Block: 256 threads = 4 waves; BM=32 rows.
// Wave w: rows (w&1)*16..+15, cols (w>>1)*128..+127 (8 col-frags of 16).
// A: direct global->register (fp32->bf16 in-reg), never staged in LDS.
// B: double-buffered LDS via global_load_lds, ONE barrier per K-iter:
//    barrier (tile kt landed) -> issue stage(kt+1) into other buf -> compute kt.
// ---------------------------------------------------------------------------
__global__ __launch_bounds__(256) void tree_head_kernel(
    const float* __restrict__ x, const unsigned short* __restrict__ Wb,
    const float* __restrict__ b_final, const float* __restrict__ wu1,
    const float* __restrict__ b1, const float* __restrict__ wu2,
    const float* __restrict__ b2, float* __restrict__ out) {
  __shared__ char smem[65536];                 // 2 x 32KB B buffers; epilogue Ls aliases

  const int tid  = threadIdx.x;
  const int lane = tid & 63;
  const int wave = tid >> 6;
  const int row0 = blockIdx.x * BM;

  const int nbase = (wave >> 1) * 128;         // this wave's column base
  const int mrow  = row0 + (wave & 1) * 16 + (lane & 15);   // this lane's A row

  f32x4 acc[8];
#pragma unroll
  for (int i = 0; i < 8; ++i)
#pragma unroll
    for (int j = 0; j < 4; ++j) acc[i][j] = 0.0f;

  // Per-lane A source: row mrow, k-offset (lane>>4)*8 within each 32-wide k-step
  const float* asrc = x + (size_t)mrow * D_FEAT + ((lane >> 4) << 3);

  // ---- prologue: prefetch A(kt=0) into regs; issue B stage(kt=0) ----------
  f32x4 a0 = *(const f32x4*)(asrc + 0);
  f32x4 a1 = *(const f32x4*)(asrc + 4);
  f32x4 a2 = *(const f32x4*)(asrc + 32);
  f32x4 a3 = *(const f32x4*)(asrc + 36);
  {
    const char* wsrc = (const char*)Wb;        // tile 0
#pragma unroll
    for (int i = 0; i < 8; ++i) {
      int off = i * 4096 + wave * 1024;
      __builtin_amdgcn_global_load_lds(
          (const __attribute__((address_space(1))) void*)(wsrc + off + lane * 16),
          (__attribute__((address_space(3))) void*)(smem + off), 16, 0, 0);
    }
  }

  for (int kt = 0; kt < K_ITERS; ++kt) {
    char* Bs = smem + (kt & 1) * 32768;
    __syncthreads();   // implicit vmcnt drain: B[kt] landed; other buf consumed

    // ---- issue stage of B[kt+1] into the other buffer (flies during compute)
    if (kt + 1 < K_ITERS) {
      const char* wsrc = (const char*)Wb + (size_t)(kt + 1) * W_TILE_BYTES;
      char* Bn = smem + ((kt + 1) & 1) * 32768;
#pragma unroll
      for (int i = 0; i < 8; ++i) {
        int off = i * 4096 + wave * 1024;
        __builtin_amdgcn_global_load_lds(
            (const __attribute__((address_space(1))) void*)(wsrc + off + lane * 16),
            (__attribute__((address_space(3))) void*)(Bn + off), 16, 0, 0);
      }
    }

    // ---- convert this tile's prefetched A to bf16 fragments ---------------
    s16x8 af0, af1;
#pragma unroll
    for (int j = 0; j < 4; ++j) {
      af0[j]     = (short)f2bf(a0[j]);
      af0[4 + j] = (short)f2bf(a1[j]);
      af1[j]     = (short)f2bf(a2[j]);
      af1[4 + j] = (short)f2bf(a3[j]);
    }

    // ---- prefetch A for kt+1 (in flight during compute) -------------------
    if (kt + 1 < K_ITERS) {
      const float* p = asrc + (kt + 1) * BK;
      a0 = *(const f32x4*)(p + 0);
      a1 = *(const f32x4*)(p + 4);
      a2 = *(const f32x4*)(p + 32);
      a3 = *(const f32x4*)(p + 36);
    }

    // ---- compute: 2 k-steps x 8 col-frags of 16x16x32 bf16 MFMA -----------
#pragma unroll
    for (int ks = 0; ks < 2; ++ks) {
      s16x8 a = ks ? af1 : af0;
      int sl = ks * 4 + (lane >> 4);    // logical 16B k-slot
#pragma unroll
      for (int nf = 0; nf < 8; ++nf) {
        int n = nbase + nf * 16 + (lane & 15);
        s16x8 b = *(const s16x8*)(Bs + n * 128 + ((sl ^ (n & 7)) << 4));
        acc[nf] = __builtin_amdgcn_mfma_f32_16x16x32_bf16(a, b, acc[nf], 0, 0, 0);
      }
    }
  }

  __syncthreads();   // all ds_reads done before smem reuse as Ls

  // ---- epilogue: logits -> LDS, column-major stride 33 ---------------------
  float* Ls = (float*)smem;            // Ls[col*33 + row], col < 248 (32736 B)
  const int c0 = lane & 15;
  const int r4 = (wave & 1) * 16 + ((lane >> 4) << 2);
#pragma unroll
  for (int nf = 0; nf < 8; ++nf) {
    int col = nbase + nf * 16 + c0;
    if (col < N_OUT) {
#pragma unroll
      for (int i = 0; i < 4; ++i) Ls[col * 33 + r4 + i] = acc[nf][i];
    }
  }
  __syncthreads();

  // 8 threads per row: part p owns root i=p entirely (u1, level-1, level-2).
  const int p = tid & 7;
  const int r = tid >> 3;              // 0..31
  float* orow = out + (size_t)(row0 + r) * N_OUT;

  float ui = Ls[p * 33 + r] + b_final[p];
  orow[p] = ui;

  // level-1: softmax over 6, then u2 = p1 * u1
  float lg[6];
  float mx = -1e30f;
#pragma unroll
  for (int c = 0; c < 6; ++c) {
    lg[c] = Ls[(8 + p * 6 + c) * 33 + r] + ui * wu1[p * 6 + c] + b1[p * 6 + c];
    mx = fmaxf(mx, lg[c]);
  }
  float s = 0.0f;
#pragma unroll
  for (int c = 0; c < 6; ++c) { lg[c] = __expf(lg[c] - mx); s += lg[c]; }
  float sc = ui / s;
  float u2v[6];
#pragma unroll
  for (int c = 0; c < 6; ++c) {
    u2v[c] = lg[c] * sc;
    orow[8 + p * 6 + c] = u2v[c];
  }

  // level-2: 6 groups of 4, u3 = p2 * u2
#pragma unroll
  for (int j = 0; j < 6; ++j) {
    int g = p * 6 + j;
    float ug = u2v[j];
    float l2[4];
    float m2 = -1e30f;
#pragma unroll
    for (int c = 0; c < 4; ++c) {
      l2[c] = Ls[(56 + g * 4 + c) * 33 + r] + ug * wu2[g * 4 + c] + b2[g * 4 + c];
      m2 = fmaxf(m2, l2[c]);
    }
    float s2 = 0.0f;
#pragma unroll
    for (int c = 0; c < 4; ++c) { l2[c] = __expf(l2[c] - m2); s2 += l2[c]; }
    float sc2 = ug / s2;
    f32x4 o;
#pragma unroll
    for (int c = 0; c < 4; ++c) o[c] = l2[c] * sc2;
    *(f32x4*)(orow + 56 + g * 4) = o;   // (row*992 + 224 + 16g) is 16B-aligned
  }
}

// ---------------------------------------------------------------------------
extern "C" void kernel_launch(void* const* d_in, const int* in_sizes, int n_in,
                              void* d_out, int out_size, void* d_ws, size_t ws_size,
                              hipStream_t stream) {
  const float* x   = (const float*)d_in[0];
  const float* Wf  = (const float*)d_in[1];
  const float* bf  = (const float*)d_in[2];
  const float* Wp1 = (const float*)d_in[3];
  const float* wu1 = (const float*)d_in[4];
  const float* b1  = (const float*)d_in[5];
  const float* Wp2 = (const float*)d_in[6];
  const float* wu2 = (const float*)d_in[7];
  const float* b2  = (const float*)d_in[8];
  float* out = (float*)d_out;
  unsigned short* Wb = (unsigned short*)d_ws;   // 655,360 B packed bf16 weights

  pack_w_kernel<<<1280, 256, 0, stream>>>(Wf, Wp1, Wp2, Wb);
  tree_head_kernel<<<16384 / BM, 256, 0, stream>>>(x, Wb, bf, wu1, b1, wu2, b2, out);
}